// Round 17
// baseline (199.218 us; speedup 1.0000x reference)
//
#include <hip/hip_runtime.h>
#include <stdint.h>

#define T_LEN 1460
#define NCH 146                    // chunks of 10 steps
#define CSZ 10
#define STEPB 576                  // per-step LDS: A 256 | B 256 | V 64
#define CHB (CSZ * STEPB)          // 5760 per chunk
// pring: ring-4 of chunks (chunk c in slot c&3; written region c-1 by
// producers, read regions c (w1 ss: A.xy,V.xy), c+1 (w0 su: A.zw,V.z),
// c+2 (w1 linear: B); slot reused by chunk c+4 at region c+3 > c+2. OK)

__device__ __forceinline__ float sigmf(float x) {
    float e = __builtin_amdgcn_exp2f(-1.44269504f * x);
    return __builtin_amdgcn_rcpf(1.0f + e);
}
__device__ __forceinline__ float rcpf(float x) { return __builtin_amdgcn_rcpf(x); }
__device__ __forceinline__ float lanef(float x, int l) {
    return __int_as_float(__builtin_amdgcn_readlane(__float_as_int(x), l));
}

// sum over a 16-lane row via full-rate DPP adds; result broadcast to the row
__device__ __forceinline__ float row_sum16(float x) {
    x += __int_as_float(__builtin_amdgcn_update_dpp(0, __float_as_int(x), 0xB1, 0xF, 0xF, true));
    x += __int_as_float(__builtin_amdgcn_update_dpp(0, __float_as_int(x), 0x4E, 0xF, 0xF, true));
    x += __int_as_float(__builtin_amdgcn_update_dpp(0, __float_as_int(x), 0x141, 0xF, 0xF, true));
    x += __int_as_float(__builtin_amdgcn_update_dpp(0, __float_as_int(x), 0x140, 0xF, 0xF, true));
    return x;
}

// ---------------------------------------------------------------------------
// Fused kernel: 256 blocks (1 basin each) x 4 waves.
//   w2,w3: producers — raw lstm_out/xc -> sigmoid-mapped params into pring
//   w1   : ss-chain (chunk r) -> {qf,qu_in}; linear reservoirs (chunk r-2) + out
//   w0   : su-chain (chunk r-1) — the irreducible serial latency core
// Sync: one __syncthreads per region (barrier drain = the whole ledger).
// Intra-region buffer disjointness and ring lifetimes audited in comments.
// ---------------------------------------------------------------------------
__global__ __launch_bounds__(256, 1) void shm_fused_kernel(
    const float* __restrict__ xc,   // [B, T, 3]
    const float* __restrict__ lo,   // [B, T, 8, 16]
    float* __restrict__ out)        // [B, T]
{
    __shared__ __align__(16) char pring[4 * CHB];   // 23040 B
    __shared__ float qin[2][CSZ][16];   // ss->su  (chunk c slot c&1: w 'r', r 'r+1')
    __shared__ float qfr[2][CSZ][16];   // ss->lin (chunk c slot c&1: w 'r', r 'r+2'; same-wave read-before-write)
    __shared__ float quo[2][CSZ][16];   // su->lin (chunk c slot c&1: w 'r+1', r 'r+2')

    const int lane = threadIdx.x & 63;
    const int wid  = threadIdx.x >> 6;
    const int m    = lane & 15;
    const float* xrow = xc + (size_t)blockIdx.x * T_LEN * 3;
    const float* lrow = lo + (size_t)blockIdx.x * T_LEN * 128;
    float* op = out + (size_t)blockIdx.x * T_LEN;

    // per-wave state (each wave uses its subset)
    float ss = 0.f, su = 5.f, sf = 1.f, si = 10.f, sb = 15.f, qk = 0.f;

    // ---------------- producer lane constants (kernel-A math, r2 layout) ----
    const int ip = lane >> 3;            // param 0..7 (2 models per lane)
    const int mm = (2 * lane) & 15;
    const float Ac = (ip==1)?10.f:(ip==2)?20.f:(ip==3)?1.f:
                     (ip==5)?1.f:(ip==6)?1.f:(ip==7)?10.f:0.f;
    const float Bc = (ip==0)?10.f:(ip==1)?50.f:(ip==2)?680.f:(ip==3)?5.f:
                     (ip==4)?1.f:(ip==5)?19.f:(ip==6)?99.f:990.f;
    const bool dorcp = (ip >= 5);        // kf,ki,kb stored as reciprocals
    const bool dosm  = (ip == 0);        // dd stored as sm = tpos*dd
    const int wroff = (ip < 4 ? 0 : 256) + mm * 16 + (ip & 3) * 4;
    const int pw = wid - 2;              // producer index 0,1

#define PRODUCE(c) {                                                          \
    char* sb_ = pring + ((c) & 3) * CHB;                                      \
    const int t0_ = (c) * CSZ;                                                \
    float2 raw[5]; float xv[5];                                               \
    _Pragma("unroll") for (int i = 0; i < 5; ++i) {                           \
        const int tl = pw + 2 * i;                                            \
        raw[i] = *(const float2*)(lrow + (size_t)(t0_ + tl) * 128 + 2 * lane);\
        xv[i]  = (lane < 3) ? xrow[(size_t)(t0_ + tl) * 3 + lane] : 0.f;      \
    }                                                                         \
    _Pragma("unroll") for (int i = 0; i < 5; ++i) {                           \
        const int tl = pw + 2 * i;                                            \
        const float temp = lanef(xv[i], 2);                                   \
        const float tpos = fmaxf(temp, 0.f);                                  \
        float v0 = fmaf(sigmf(raw[i].x), Bc, Ac);                             \
        float v1 = fmaf(sigmf(raw[i].y), Bc, Ac);                             \
        if (dorcp) { v0 = rcpf(v0); v1 = rcpf(v1); }                          \
        if (dosm)  { v0 *= tpos;    v1 *= tpos; }                             \
        *(float*)(sb_ + tl * STEPB + wroff)      = v0;                        \
        *(float*)(sb_ + tl * STEPB + wroff + 16) = v1;                        \
        if (lane < 16) {                                                      \
            const float prec = lanef(xv[i], 0), pet = lanef(xv[i], 1);        \
            const int comp = lane & 3;                                        \
            const float vv = (comp == 0) ? (temp < 0.f ? prec : 0.f)          \
                           : (comp == 1) ? (temp < 0.f ? 0.f : prec)          \
                           : (comp == 2) ? 0.9f * pet : 0.f;                  \
            *(float*)(sb_ + tl * STEPB + 512 + lane * 4) = vv;                \
        }                                                                     \
    } }

#define FOR10(X) X(0) X(1) X(2) X(3) X(4) X(5) X(6) X(7) X(8) X(9)

// w1: load linear inputs of chunk cl=r-2 FIRST (qfr slot == hs; must read
// before SSSTEP overwrites it — same-wave program order guarantees this).
#define LINLOAD(J)                                                            \
    float4 LB##J = make_float4(0.f,0.f,0.f,0.f); float LF##J = 0.f, LO##J = 0.f; \
    if (doLin) {                                                              \
        LB##J = *(const float4*)(sbl + (J) * STEPB + 256 + m * 16);           \
        LF##J = qfr[hl][J][m];                                                \
        LO##J = quo[hl][J][m];                                                \
    }

#define SSSTEP(J) {                                                           \
    float4 A_ = *(const float4*)(sbs + (J) * STEPB + m * 16);                 \
    float4 V_ = *(const float4*)(sbs + (J) * STEPB + 512 + (m & ~3) * 4);     \
    const float qs_out = fminf(ss, A_.x);                                     \
    ss = (ss - qs_out) + V_.x;                                                \
    const float qsp = qs_out + V_.y;                                          \
    const float qf_ = fmaxf(0.f, qsp - A_.y);                                 \
    const float qu_ = fminf(qsp, A_.y);                                       \
    qin[hs][J][m] = qu_;                                                      \
    qfr[hs][J][m] = qf_; }

#define LINSTEP(J, tt) {                                                      \
    sf += LF##J; const float qf_out = sf * LB##J.y; sf -= qf_out;             \
    const float qi_in = LO##J * LB##J.x;                                      \
    si += qi_in; const float qi_out = si * LB##J.z; si -= qi_out;             \
    sb += (LO##J - qi_in); const float qb_out = sb * LB##J.w; sb -= qb_out;   \
    const float q_ = row_sum16(qf_out + qi_out + qb_out) * 0.0625f;           \
    qk = (m == ((tt) & 15)) ? q_ : qk;                                        \
    if (((tt) & 15) == 15) op[((tt) & ~15) + m] = qk; }

#define SUSTEP(J) {                                                           \
    float4 A_ = *(const float4*)(sbu + (J) * STEPB + m * 16);                 \
    float4 V_ = *(const float4*)(sbu + (J) * STEPB + 512 + (m & ~3) * 4);     \
    const float sumax = A_.z, beta = A_.w, et09 = V_.z;                       \
    const float inv = rcpf(sumax);                                            \
    const float pwp = 0.8f * sumax;                                           \
    const float e_i = et09 * inv;                                             \
    const float qu_in = qin[hu][J][m];                                        \
    const float u = su * inv;                                                 \
    const float psi = __builtin_amdgcn_exp2f(beta * __builtin_amdgcn_logf(u));\
    const float su_t = fmaf(qu_in, 1.f - psi, su);                            \
    const float su2 = fminf(su_t, sumax);                                     \
    const float ovf = fmaxf(0.f, su_t - sumax);                               \
    const float qu_out = fmaf(qu_in, psi, ovf);                               \
    const float ret = (su2 <= pwp) ? su2 * e_i : et09;                        \
    su = fmaxf(0.f, su2 - ret);                                               \
    quo[hu][J][m] = qu_out; }

    // prologue: producers fill chunk 0
    if (wid >= 2) PRODUCE(0)
    __syncthreads();

    // regions r: producers chunk r+1 | w1 ss chunk r + linear chunk r-2 | w0 su chunk r-1
    for (int r = 0; r <= 147; ++r) {
        if (wid >= 2) {
            if (r <= 144) PRODUCE(r + 1)
        } else if (wid == 1) {
            if (lane < 16) {
                const bool doLin = (r >= 2);
                const int cl = doLin ? (r - 2) : 0;
                const int hl = cl & 1;
                const char* sbl = pring + (cl & 3) * CHB;
                FOR10(LINLOAD)
                if (r <= 145) {
                    const char* sbs = pring + (r & 3) * CHB;
                    const int hs = r & 1;
                    FOR10(SSSTEP)
                }
                if (doLin) {
                    const int t0 = cl * CSZ;
                    LINSTEP(0, t0)     LINSTEP(1, t0 + 1) LINSTEP(2, t0 + 2)
                    LINSTEP(3, t0 + 3) LINSTEP(4, t0 + 4) LINSTEP(5, t0 + 5)
                    LINSTEP(6, t0 + 6) LINSTEP(7, t0 + 7) LINSTEP(8, t0 + 8)
                    LINSTEP(9, t0 + 9)
                }
            }
        } else {
            if (r >= 1 && r <= 146 && lane < 16) {
                const int cu = r - 1;
                const char* sbu = pring + (cu & 3) * CHB;
                const int hu = cu & 1;
                FOR10(SUSTEP)
            }
        }
        __syncthreads();
    }

    // tail: lanes 0..3 of w1 hold q for t = 1456..1459
    if (wid == 1 && lane < 4) op[1456 + lane] = qk;

#undef PRODUCE
#undef FOR10
#undef LINLOAD
#undef SSSTEP
#undef LINSTEP
#undef SUSTEP
}

extern "C" void kernel_launch(void* const* d_in, const int* in_sizes, int n_in,
                              void* d_out, int out_size, void* d_ws, size_t ws_size,
                              hipStream_t stream) {
    const float* xc = (const float*)d_in[0];   // [256,1460,3]
    const float* lo = (const float*)d_in[1];   // [256,1460,128]
    float* out = (float*)d_out;                // [256,1460,1]
    (void)d_ws; (void)ws_size;                 // no workspace needed

    shm_fused_kernel<<<dim3(256), dim3(256), 0, stream>>>(xc, lo, out);
}